// Round 3
// baseline (262.302 us; speedup 1.0000x reference)
//
#include <hip/hip_runtime.h>
#include <hip/hip_bf16.h>

typedef __bf16 bf16x8 __attribute__((ext_vector_type(8)));
typedef float f32x4 __attribute__((ext_vector_type(4)));
typedef unsigned int u32;
typedef u32 u32x4 __attribute__((ext_vector_type(4)));

#define MFMA(a, b, c) __builtin_amdgcn_mfma_f32_16x16x32_bf16((a), (b), (c), 0, 0, 0)

static __device__ __forceinline__ bf16x8 ld8(const __bf16* p) {
  return *reinterpret_cast<const bf16x8*>(p);
}

// pack two f32 -> bf16x2 in one u32 (compiler fuses to v_cvt_pk_bf16_f32)
static __device__ __forceinline__ u32 pkbf(float a, float b) {
  union { __bf16 h; unsigned short s; } x, y;
  x.h = (__bf16)a; y.h = (__bf16)b;
  return (u32)x.s | ((u32)y.s << 16);
}

// Stage 16 elements into LDS, converting fp32 -> bf16 on the fly when needed.
template<bool SRC_F32>
static __device__ __forceinline__ void stage16(__bf16* __restrict__ dst,
                                               const void* __restrict__ srcv) {
  if constexpr (SRC_F32) {
    const float* src = (const float*)srcv;
#pragma unroll
    for (int j = 0; j < 2; ++j) {
      f32x4 a = *reinterpret_cast<const f32x4*>(src + j * 8);
      f32x4 b = *reinterpret_cast<const f32x4*>(src + j * 8 + 4);
      bf16x8 o;
#pragma unroll
      for (int i = 0; i < 4; ++i) {
        o[i] = (__bf16)a[i];
        o[i + 4] = (__bf16)b[i];
      }
      *reinterpret_cast<bf16x8*>(dst + j * 8) = o;
    }
  } else {
    const __bf16* src = (const __bf16*)srcv;
#pragma unroll
    for (int j = 0; j < 2; ++j)
      *reinterpret_cast<bf16x8*>(dst + j * 8) = *reinterpret_cast<const bf16x8*>(src + j * 8);
  }
}

// C[m][n] = sum_k A[m][k] * W[n][k]  (A @ W^T), W fp32 (N x K) row-major.
// Tile 128x128, BK=32, 4 waves 2x2, each wave 64x64 (4x4 MFMA frags).
// SPLIT mode (GEMM1): cols [0,2048) -> QK buffer (row stride 2048, bf16);
//                     cols [2048,3072) -> VT buffer [b*1024 + (col-2048)][t] bf16.
template<bool A_F32, bool OUT_BF16, bool SPLIT>
__global__ __launch_bounds__(256)
void gemm_bt(const void* __restrict__ Av, const float* __restrict__ W,
             void* __restrict__ Cv, __bf16* __restrict__ VT,
             int M, int N, int K) {
  __shared__ __bf16 lA[128 * 40];
  __shared__ __bf16 lB[128 * 40];

  const int tid = threadIdx.x;
  const int ntiles = N >> 7;
  const int mt = blockIdx.x / ntiles;
  const int nt = blockIdx.x % ntiles;
  const int m0 = mt << 7, n0 = nt << 7;
  const int lane = tid & 63, w = tid >> 6;
  const int wm = (w >> 1) << 6;
  const int wn = (w & 1) << 6;
  const int fr = lane & 15, fg = lane >> 4;
  const int srow = tid >> 1, scol = (tid & 1) << 4;

  f32x4 acc[4][4] = {};

  for (int k0 = 0; k0 < K; k0 += 32) {
    __syncthreads();
    if constexpr (A_F32)
      stage16<true>(lA + srow * 40 + scol,
                    (const float*)Av + (size_t)(m0 + srow) * K + k0 + scol);
    else
      stage16<false>(lA + srow * 40 + scol,
                     (const __bf16*)Av + (size_t)(m0 + srow) * K + k0 + scol);
    stage16<true>(lB + srow * 40 + scol, W + (size_t)(n0 + srow) * K + k0 + scol);
    __syncthreads();

    bf16x8 af[4], bfr[4];
#pragma unroll
    for (int m = 0; m < 4; ++m)
      af[m] = ld8(lA + (wm + m * 16 + fr) * 40 + fg * 8);
#pragma unroll
    for (int n = 0; n < 4; ++n)
      bfr[n] = ld8(lB + (wn + n * 16 + fr) * 40 + fg * 8);
#pragma unroll
    for (int m = 0; m < 4; ++m)
#pragma unroll
      for (int n = 0; n < 4; ++n)
        acc[m][n] = MFMA(af[m], bfr[n], acc[m][n]);
  }

  // C/D layout: col = lane&15, row = (lane>>4)*4 + reg
#pragma unroll
  for (int m = 0; m < 4; ++m) {
#pragma unroll
    for (int n = 0; n < 4; ++n) {
#pragma unroll
      for (int r = 0; r < 4; ++r) {
        int row = m0 + wm + m * 16 + fg * 4 + r;
        int col = n0 + wn + n * 16 + fr;
        if constexpr (SPLIT) {
          int b = row >> 11, t = row & 2047;
          if (col >= 2048) {
            VT[((size_t)(b << 10) + (col - 2048)) * 2048 + t] = (__bf16)acc[m][n][r];
          } else {
            ((__bf16*)Cv)[(size_t)row * 2048 + col] = (__bf16)acc[m][n][r];
          }
        } else if constexpr (OUT_BF16) {
          ((__bf16*)Cv)[(size_t)row * N + col] = (__bf16)acc[m][n][r];
        } else {
          ((float*)Cv)[(size_t)row * N + col] = acc[m][n][r];
        }
      }
    }
  }
}

// Barrier-free causal flash attention, fully in-register softmax (swapped QK^T).
// qk: (B*T, 2048) bf16, col = s(0=Q,1=K)*1024 + h*64 + dk.
// vt: (B*1024, 2048) bf16 = V^T per (b,h): row b*1024 + h*64 + dk, col = t.
// out: (B*T, 1024) bf16.
// Grid: 1024 blocks x 256. Each wave = one independent 16-row q-tile (LPT order).
// S^T = mfma(K, Q): C col = lane&15 = q-row, C row = fg*4+r = key-sub.
// Each lane owns one q-row's stats (m, l scalar), keys fg*4+r per 16-key tile.
__global__ __launch_bounds__(256)
void attn_causal3(const __bf16* __restrict__ qk, const __bf16* __restrict__ vt,
                  __bf16* __restrict__ out) {
  constexpr float SC2 = 0.125f * 1.4426950408889634f;  // scale * log2(e)
  constexpr float NEG = -1e30f;

  const int tid = threadIdx.x;
  const int lane = tid & 63, w = tid >> 6;
  const int fr = lane & 15, fg = lane >> 4;
  const int g = blockIdx.x * 4 + w;
  const int qt = 127 - (g >> 5);
  const int bh = g & 31;
  const int b = bh >> 4, h = bh & 15;
  const int q0 = qt << 4;
  const int hoff = h * 64;
  const size_t qkbase = (size_t)b * (2048 * 2048);
  const size_t vbase = (size_t)((b << 10) | hoff) * 2048;

  // Q fragments (B-operand): col = fr = q-row, k = c*32 + fg*8 + i
  bf16x8 qf[2];
#pragma unroll
  for (int c = 0; c < 2; ++c)
    qf[c] = ld8(qk + qkbase + (size_t)(q0 + fr) * 2048 + hoff + c * 32 + fg * 8);

  f32x4 o[4] = {};   // O accum: C col = dk-sub (tile n), C row = fg*4+r = q-row
  float m = NEG;     // running max (log2 domain), q-row = fr
  float l = 0.f;     // running sum, q-row = fr

  const int nkt = (q0 + 79) >> 6;  // 64-key tiles covering keys [0, q0+16)
  for (int kt = 0; kt < nkt; ++kt) {
    const int k0 = kt << 6;

    // S^T = K Q^T : s[n][r] = S[key=k0+n*16+fg*4+r][q=q0+fr] * (pre-scale)
    f32x4 s[4] = {};
#pragma unroll
    for (int n = 0; n < 4; ++n) {
      const __bf16* kp = qk + qkbase + (size_t)(k0 + n * 16 + fr) * 2048 + 1024 + hoff;
#pragma unroll
      for (int c = 0; c < 2; ++c)
        s[n] = MFMA(ld8(kp + c * 32 + fg * 8), qf[c], s[n]);
    }

    // issue V loads early (latency hides under softmax)
    bf16x8 vf[2][4];
#pragma unroll
    for (int c = 0; c < 2; ++c)
#pragma unroll
      for (int n = 0; n < 4; ++n)
        vf[c][n] = ld8(vt + vbase + (size_t)(n * 16 + fr) * 2048 + k0 + c * 32 + fg * 8);

    // scale into log2 domain + causal mask (only last tile can violate)
    const bool diag = (kt == nkt - 1);
    float sv[4][4];
#pragma unroll
    for (int n = 0; n < 4; ++n)
#pragma unroll
      for (int r = 0; r < 4; ++r) {
        float x = s[n][r] * SC2;
        if (diag && (k0 + n * 16 + fg * 4 + r > q0 + fr)) x = NEG;
        sv[n][r] = x;
      }

    // row max: in-register tree (16 vals) + 2 cross-fg shuffles
    float t0 = fmaxf(fmaxf(sv[0][0], sv[0][1]), fmaxf(sv[0][2], sv[0][3]));
    float t1 = fmaxf(fmaxf(sv[1][0], sv[1][1]), fmaxf(sv[1][2], sv[1][3]));
    float t2 = fmaxf(fmaxf(sv[2][0], sv[2][1]), fmaxf(sv[2][2], sv[2][3]));
    float t3 = fmaxf(fmaxf(sv[3][0], sv[3][1]), fmaxf(sv[3][2], sv[3][3]));
    float rm = fmaxf(fmaxf(t0, t1), fmaxf(t2, t3));
    rm = fmaxf(rm, __shfl_xor(rm, 16));
    rm = fmaxf(rm, __shfl_xor(rm, 32));

    // defer-max (T13): only rescale when the new tile max pushes past m+16
    if (!__all(rm <= m + 16.f)) {
      float mnew = fmaxf(m, rm);
      float alpha = __builtin_exp2f(m - mnew);
      m = mnew;
      l *= alpha;
      float ao[4];  // alpha for O rows q = fg*4+r, held by lane fg*4+r
#pragma unroll
      for (int r = 0; r < 4; ++r)
        ao[r] = __shfl(alpha, fg * 4 + r);
#pragma unroll
      for (int n = 0; n < 4; ++n)
#pragma unroll
        for (int r = 0; r < 4; ++r)
          o[n][r] *= ao[r];
    }

    // P = exp2(sv - m)  (bounded by 2^16 under defer-max)
    float p[4][4];
#pragma unroll
    for (int n = 0; n < 4; ++n)
#pragma unroll
      for (int r = 0; r < 4; ++r)
        p[n][r] = __builtin_exp2f(sv[n][r] - m);

    // row sum: tree + 2 shuffles
    float u0 = (p[0][0] + p[0][1]) + (p[0][2] + p[0][3]);
    float u1 = (p[1][0] + p[1][1]) + (p[1][2] + p[1][3]);
    float u2 = (p[2][0] + p[2][1]) + (p[2][2] + p[2][3]);
    float u3 = (p[3][0] + p[3][1]) + (p[3][2] + p[3][3]);
    float rs = (u0 + u1) + (u2 + u3);
    rs += __shfl_xor(rs, 16);
    rs += __shfl_xor(rs, 32);
    l += rs;

    // pack P to bf16 pairs: wpk[n][h] = keys (n*16+fg*4+2h, +2h+1) for q-row fr
    u32 wpk[4][2];
#pragma unroll
    for (int n = 0; n < 4; ++n) {
      wpk[n][0] = pkbf(p[n][0], p[n][1]);
      wpk[n][1] = pkbf(p[n][2], p[n][3]);
    }

    // Redistribute P^T -> PV A-fragments (8 fully-utilized bpermutes).
    // Instance e: srcLane = fr + 16*(2(fg&1) + ((fg>>1)^e))  [bijection],
    // source sends wpk[2c + ((fg&1)^e)][h]; dest gets word n = 2c + (fg>>1).
    u32 rcv[2][2][2];  // [e][c][h]
#pragma unroll
    for (int e = 0; e < 2; ++e) {
      const int src = fr + ((((fg & 1) << 1) | ((fg >> 1) ^ e)) << 4);
      const bool tsel = ((fg & 1) ^ e) != 0;
#pragma unroll
      for (int c = 0; c < 2; ++c)
#pragma unroll
        for (int hh = 0; hh < 2; ++hh) {
          u32 v = tsel ? wpk[(c << 1) | 1][hh] : wpk[(c << 1) | 0][hh];
          rcv[e][c][hh] = (u32)__shfl((int)v, src);
        }
    }
    // place: pa[c] word j=2a+h comes from instance e = (fg>>1)^a
    const bool hi = (fg >> 1) != 0;
    u32x4 w0, w1;
#pragma unroll
    for (int a = 0; a < 2; ++a)
#pragma unroll
      for (int hh = 0; hh < 2; ++hh) {
        w0[2 * a + hh] = hi ? rcv[a ^ 1][0][hh] : rcv[a][0][hh];
        w1[2 * a + hh] = hi ? rcv[a ^ 1][1][hh] : rcv[a][1][hh];
      }
    bf16x8 pa[2];
    pa[0] = __builtin_bit_cast(bf16x8, w0);
    pa[1] = __builtin_bit_cast(bf16x8, w1);

    // O += P V
#pragma unroll
    for (int c = 0; c < 2; ++c)
#pragma unroll
      for (int n = 0; n < 4; ++n)
        o[n] = MFMA(pa[c], vf[c][n], o[n]);
  }

  // normalize: linv per q-row fr -> transpose to O rows via 4 bpermutes
  float linv = 1.f / l;
  float lo[4];
#pragma unroll
  for (int r = 0; r < 4; ++r)
    lo[r] = __shfl(linv, fg * 4 + r);
#pragma unroll
  for (int n = 0; n < 4; ++n)
#pragma unroll
    for (int r = 0; r < 4; ++r) {
      int t = q0 + fg * 4 + r;
      out[((size_t)(b * 2048 + t)) * 1024 + hoff + n * 16 + fr] = (__bf16)(o[n][r] * lo[r]);
    }
}

extern "C" void kernel_launch(void* const* d_in, const int* in_sizes, int n_in,
                              void* d_out, int out_size, void* d_ws, size_t ws_size,
                              hipStream_t stream) {
  const float* x = (const float*)d_in[0];       // (2,2048,1024) fp32
  const float* w_qkv = (const float*)d_in[1];   // (3072,1024) fp32
  const float* w_o = (const float*)d_in[2];     // (1024,1024) fp32
  float* out = (float*)d_out;                   // (2,2048,1024) fp32

  const int M = 4096;  // B*T
  __bf16* qk = (__bf16*)d_ws;                                    // 4096 x 2048 bf16
  __bf16* vt = (__bf16*)((char*)d_ws + (size_t)M * 2048 * 2);    // 2048 x 2048 bf16 (V^T)
  __bf16* attn = (__bf16*)((char*)d_ws + (size_t)M * 3072 * 2);  // 4096 x 1024 bf16

  // GEMM1: qkv = x @ W_qkv^T ; Q,K -> qk buffer, V -> vt transposed
  gemm_bt<true, true, true><<<(M / 128) * (3072 / 128), 256, 0, stream>>>(
      (const void*)x, w_qkv, (void*)qk, vt, M, 3072, 1024);

  // causal attention (barrier-free, in-register softmax, LPT order)
  attn_causal3<<<1024, 256, 0, stream>>>(qk, vt, attn);

  // GEMM2: out = attn @ W_o^T (fp32 out)
  gemm_bt<false, false, false><<<(M / 128) * (1024 / 128), 256, 0, stream>>>(
      (const void*)attn, w_o, (void*)out, nullptr, M, 1024, 1024);
}

// Round 4
// 251.692 us; speedup vs baseline: 1.0422x; 1.0422x over previous
//
#include <hip/hip_runtime.h>
#include <hip/hip_bf16.h>

typedef __bf16 bf16x8 __attribute__((ext_vector_type(8)));
typedef float f32x4 __attribute__((ext_vector_type(4)));
typedef unsigned int u32;
typedef u32 u32x4 __attribute__((ext_vector_type(4)));

#define MFMA(a, b, c) __builtin_amdgcn_mfma_f32_16x16x32_bf16((a), (b), (c), 0, 0, 0)

static __device__ __forceinline__ bf16x8 ld8(const __bf16* p) {
  return *reinterpret_cast<const bf16x8*>(p);
}

// pack two f32 -> bf16x2 in one u32 (compiler fuses to v_cvt_pk_bf16_f32)
static __device__ __forceinline__ u32 pkbf(float a, float b) {
  union { __bf16 h; unsigned short s; } x, y;
  x.h = (__bf16)a; y.h = (__bf16)b;
  return (u32)x.s | ((u32)y.s << 16);
}

// Stage 16 elements into LDS, converting fp32 -> bf16 on the fly when needed.
template<bool SRC_F32>
static __device__ __forceinline__ void stage16(__bf16* __restrict__ dst,
                                               const void* __restrict__ srcv) {
  if constexpr (SRC_F32) {
    const float* src = (const float*)srcv;
#pragma unroll
    for (int j = 0; j < 2; ++j) {
      f32x4 a = *reinterpret_cast<const f32x4*>(src + j * 8);
      f32x4 b = *reinterpret_cast<const f32x4*>(src + j * 8 + 4);
      bf16x8 o;
#pragma unroll
      for (int i = 0; i < 4; ++i) {
        o[i] = (__bf16)a[i];
        o[i + 4] = (__bf16)b[i];
      }
      *reinterpret_cast<bf16x8*>(dst + j * 8) = o;
    }
  } else {
    const __bf16* src = (const __bf16*)srcv;
#pragma unroll
    for (int j = 0; j < 2; ++j)
      *reinterpret_cast<bf16x8*>(dst + j * 8) = *reinterpret_cast<const bf16x8*>(src + j * 8);
  }
}

// C[m][n] = sum_k A[m][k] * W[n][k]  (A @ W^T), W fp32 (N x K) row-major.
// Tile 128x128, BK=32, 4 waves 2x2, each wave 64x64 (4x4 MFMA frags).
// SPLIT mode (GEMM1): cols [0,2048) -> QK buffer (row stride 2048, bf16);
//                     cols [2048,3072) -> VT buffer [b*1024 + (col-2048)][t] bf16.
template<bool A_F32, bool OUT_BF16, bool SPLIT>
__global__ __launch_bounds__(256)
void gemm_bt(const void* __restrict__ Av, const float* __restrict__ W,
             void* __restrict__ Cv, __bf16* __restrict__ VT,
             int M, int N, int K) {
  __shared__ __bf16 lA[128 * 40];
  __shared__ __bf16 lB[128 * 40];

  const int tid = threadIdx.x;
  const int ntiles = N >> 7;
  const int mt = blockIdx.x / ntiles;
  const int nt = blockIdx.x % ntiles;
  const int m0 = mt << 7, n0 = nt << 7;
  const int lane = tid & 63, w = tid >> 6;
  const int wm = (w >> 1) << 6;
  const int wn = (w & 1) << 6;
  const int fr = lane & 15, fg = lane >> 4;
  const int srow = tid >> 1, scol = (tid & 1) << 4;

  f32x4 acc[4][4] = {};

  for (int k0 = 0; k0 < K; k0 += 32) {
    __syncthreads();
    if constexpr (A_F32)
      stage16<true>(lA + srow * 40 + scol,
                    (const float*)Av + (size_t)(m0 + srow) * K + k0 + scol);
    else
      stage16<false>(lA + srow * 40 + scol,
                     (const __bf16*)Av + (size_t)(m0 + srow) * K + k0 + scol);
    stage16<true>(lB + srow * 40 + scol, W + (size_t)(n0 + srow) * K + k0 + scol);
    __syncthreads();

    bf16x8 af[4], bfr[4];
#pragma unroll
    for (int m = 0; m < 4; ++m)
      af[m] = ld8(lA + (wm + m * 16 + fr) * 40 + fg * 8);
#pragma unroll
    for (int n = 0; n < 4; ++n)
      bfr[n] = ld8(lB + (wn + n * 16 + fr) * 40 + fg * 8);
#pragma unroll
    for (int m = 0; m < 4; ++m)
#pragma unroll
      for (int n = 0; n < 4; ++n)
        acc[m][n] = MFMA(af[m], bfr[n], acc[m][n]);
  }

  // C/D layout: col = lane&15, row = (lane>>4)*4 + reg
#pragma unroll
  for (int m = 0; m < 4; ++m) {
#pragma unroll
    for (int n = 0; n < 4; ++n) {
#pragma unroll
      for (int r = 0; r < 4; ++r) {
        int row = m0 + wm + m * 16 + fg * 4 + r;
        int col = n0 + wn + n * 16 + fr;
        if constexpr (SPLIT) {
          int b = row >> 11, t = row & 2047;
          if (col >= 2048) {
            VT[((size_t)(b << 10) + (col - 2048)) * 2048 + t] = (__bf16)acc[m][n][r];
          } else {
            ((__bf16*)Cv)[(size_t)row * 2048 + col] = (__bf16)acc[m][n][r];
          }
        } else if constexpr (OUT_BF16) {
          ((__bf16*)Cv)[(size_t)row * N + col] = (__bf16)acc[m][n][r];
        } else {
          ((float*)Cv)[(size_t)row * N + col] = acc[m][n][r];
        }
      }
    }
  }
}

// Causal flash attention, intra-block 4-way key-split.
// qk: (B*T, 2048) bf16, col = s(0=Q,1=K)*1024 + h*64 + dk.
// vt: (B*1024, 2048) bf16 = V^T per (b,h): row b*1024 + h*64 + dk, col = t.
// out: (B*T, 1024) bf16.
// Grid: 4096 blocks (one per (qt,bh), LPT qt-descending) x 256 threads.
// The 4 waves of a block process key-tiles round-robin (kt = w, w+4, ...),
// each with private (m, l, O); LDS combine merges the 4 partials.
// Per-wave softmax is fully in-register via swapped QK^T (S^T = mfma(K, Q)):
// C col = lane&15 = q-row, C row = fg*4+r = key-sub; stats live at q = fr.
__global__ __launch_bounds__(256)
void attn_causal4(const __bf16* __restrict__ qk, const __bf16* __restrict__ vt,
                  __bf16* __restrict__ out) {
  constexpr float SC2 = 0.125f * 1.4426950408889634f;  // scale * log2(e)
  constexpr float NEG = -1e30f;

  __shared__ float lO[4][16][65];  // [wave][q][dk], pad 65 -> <=2-way conflicts
  __shared__ float lM[4][16];
  __shared__ float lL[4][16];

  const int tid = threadIdx.x;
  const int lane = tid & 63, w = tid >> 6;
  const int fr = lane & 15, fg = lane >> 4;
  const int blk = blockIdx.x;
  const int qt = 127 - (blk >> 5);   // LPT: longest q-tiles first
  const int bh = blk & 31;
  const int b = bh >> 4, h = bh & 15;
  const int q0 = qt << 4;
  const int hoff = h * 64;
  const size_t qkbase = (size_t)b * (2048 * 2048);
  const __bf16* kb = qk + qkbase + 1024 + hoff;                  // K rows, stride 2048
  const __bf16* vtb = vt + (size_t)((b << 10) | hoff) * 2048;    // V^T rows, stride 2048

  // Q fragments (B-operand): col = fr = q-row, k = c*32 + fg*8 + i
  bf16x8 qf[2];
#pragma unroll
  for (int c = 0; c < 2; ++c)
    qf[c] = ld8(qk + qkbase + (size_t)(q0 + fr) * 2048 + hoff + c * 32 + fg * 8);

  f32x4 o[4] = {};   // per-lane: q = fg*4+r, dk = n*16+fr
  float m = NEG;     // running max (log2 domain), q-row = fr
  float l = 0.f;     // running sum, q-row = fr

  const int nkt = (q0 + 79) >> 6;  // 64-key tiles covering keys [0, q0+16)
  for (int kt = w; kt < nkt; kt += 4) {
    const int k0 = kt << 6;

    // S^T = K Q^T : s[n][r] = S[key=k0+n*16+fg*4+r][q=q0+fr] (pre-scale)
    f32x4 s[4] = {};
#pragma unroll
    for (int n = 0; n < 4; ++n) {
      const __bf16* kp = kb + (size_t)(k0 + n * 16 + fr) * 2048;
#pragma unroll
      for (int c = 0; c < 2; ++c)
        s[n] = MFMA(ld8(kp + c * 32 + fg * 8), qf[c], s[n]);
    }

    // issue V loads early (latency hides under softmax)
    bf16x8 vf[2][4];
#pragma unroll
    for (int c = 0; c < 2; ++c)
#pragma unroll
      for (int n = 0; n < 4; ++n)
        vf[c][n] = ld8(vtb + (size_t)(n * 16 + fr) * 2048 + k0 + c * 32 + fg * 8);

    // scale into log2 domain + causal mask (only last tile can violate)
    const bool diag = (kt == nkt - 1);
    float sv[4][4];
#pragma unroll
    for (int n = 0; n < 4; ++n)
#pragma unroll
      for (int r = 0; r < 4; ++r) {
        float x = s[n][r] * SC2;
        if (diag && (k0 + n * 16 + fg * 4 + r > q0 + fr)) x = NEG;
        sv[n][r] = x;
      }

    // row max: in-register tree (16 vals) + 2 cross-fg shuffles
    float t0 = fmaxf(fmaxf(sv[0][0], sv[0][1]), fmaxf(sv[0][2], sv[0][3]));
    float t1 = fmaxf(fmaxf(sv[1][0], sv[1][1]), fmaxf(sv[1][2], sv[1][3]));
    float t2 = fmaxf(fmaxf(sv[2][0], sv[2][1]), fmaxf(sv[2][2], sv[2][3]));
    float t3 = fmaxf(fmaxf(sv[3][0], sv[3][1]), fmaxf(sv[3][2], sv[3][3]));
    float rm = fmaxf(fmaxf(t0, t1), fmaxf(t2, t3));
    rm = fmaxf(rm, __shfl_xor(rm, 16));
    rm = fmaxf(rm, __shfl_xor(rm, 32));

    // defer-max (T13): only rescale when the new tile max pushes past m+16
    if (!__all(rm <= m + 16.f)) {
      float mnew = fmaxf(m, rm);
      float alpha = __builtin_exp2f(m - mnew);
      m = mnew;
      l *= alpha;
      float ao[4];  // alpha for O rows q = fg*4+r
#pragma unroll
      for (int r = 0; r < 4; ++r)
        ao[r] = __shfl(alpha, fg * 4 + r);
#pragma unroll
      for (int n = 0; n < 4; ++n)
#pragma unroll
        for (int r = 0; r < 4; ++r)
          o[n][r] *= ao[r];
    }

    // P = exp2(sv - m)  (bounded by 2^16 under defer-max)
    float p[4][4];
#pragma unroll
    for (int n = 0; n < 4; ++n)
#pragma unroll
      for (int r = 0; r < 4; ++r)
        p[n][r] = __builtin_exp2f(sv[n][r] - m);

    // row sum: tree + 2 shuffles
    float u0 = (p[0][0] + p[0][1]) + (p[0][2] + p[0][3]);
    float u1 = (p[1][0] + p[1][1]) + (p[1][2] + p[1][3]);
    float u2 = (p[2][0] + p[2][1]) + (p[2][2] + p[2][3]);
    float u3 = (p[3][0] + p[3][1]) + (p[3][2] + p[3][3]);
    float rs = (u0 + u1) + (u2 + u3);
    rs += __shfl_xor(rs, 16);
    rs += __shfl_xor(rs, 32);
    l += rs;

    // pack P to bf16 pairs: wpk[n][h] = keys (n*16+fg*4+2h, +2h+1) for q-row fr
    u32 wpk[4][2];
#pragma unroll
    for (int n = 0; n < 4; ++n) {
      wpk[n][0] = pkbf(p[n][0], p[n][1]);
      wpk[n][1] = pkbf(p[n][2], p[n][3]);
    }

    // Redistribute P^T -> PV A-fragments (8 fully-utilized bpermutes).
    // Instance e: srcLane = fr + 16*(2(fg&1) + ((fg>>1)^e))  [bijection],
    // source sends wpk[2c + ((fg&1)^e)][h]; dest gets word n = 2c + (fg>>1).
    u32 rcv[2][2][2];  // [e][c][h]
#pragma unroll
    for (int e = 0; e < 2; ++e) {
      const int src = fr + ((((fg & 1) << 1) | ((fg >> 1) ^ e)) << 4);
      const bool tsel = ((fg & 1) ^ e) != 0;
#pragma unroll
      for (int c = 0; c < 2; ++c)
#pragma unroll
        for (int hh = 0; hh < 2; ++hh) {
          u32 v = tsel ? wpk[(c << 1) | 1][hh] : wpk[(c << 1) | 0][hh];
          rcv[e][c][hh] = (u32)__shfl((int)v, src);
        }
    }
    // place: pa[c] word j=2a+h comes from instance e = (fg>>1)^a
    const bool hi = (fg >> 1) != 0;
    u32x4 w0, w1;
#pragma unroll
    for (int a = 0; a < 2; ++a)
#pragma unroll
      for (int hh = 0; hh < 2; ++hh) {
        w0[2 * a + hh] = hi ? rcv[a ^ 1][0][hh] : rcv[a][0][hh];
        w1[2 * a + hh] = hi ? rcv[a ^ 1][1][hh] : rcv[a][1][hh];
      }
    bf16x8 pa[2];
    pa[0] = __builtin_bit_cast(bf16x8, w0);
    pa[1] = __builtin_bit_cast(bf16x8, w1);

    // O += P V
#pragma unroll
    for (int c = 0; c < 2; ++c)
#pragma unroll
      for (int n = 0; n < 4; ++n)
        o[n] = MFMA(pa[c], vf[c][n], o[n]);
  }

  // ---- write partials to LDS ----
  if (fg == 0) { lM[w][fr] = m; lL[w][fr] = l; }
#pragma unroll
  for (int n = 0; n < 4; ++n)
#pragma unroll
    for (int r = 0; r < 4; ++r)
      lO[w][fg * 4 + r][n * 16 + fr] = o[n][r];
  __syncthreads();

  // ---- combine: lane (fg,fr) of wave w handles q = fg*4+r, dk = w*16+fr ----
#pragma unroll
  for (int r = 0; r < 4; ++r) {
    const int q = fg * 4 + r;
    float m0 = lM[0][q], m1 = lM[1][q], m2 = lM[2][q], m3 = lM[3][q];
    float ms = fmaxf(fmaxf(m0, m1), fmaxf(m2, m3));
    float w0 = __builtin_exp2f(m0 - ms);
    float w1 = __builtin_exp2f(m1 - ms);
    float w2 = __builtin_exp2f(m2 - ms);
    float w3 = __builtin_exp2f(m3 - ms);
    float ls = w0 * lL[0][q] + w1 * lL[1][q] + w2 * lL[2][q] + w3 * lL[3][q];
    const int dk = w * 16 + fr;
    float ov = w0 * lO[0][q][dk] + w1 * lO[1][q][dk]
             + w2 * lO[2][q][dk] + w3 * lO[3][q][dk];
    const int t = q0 + q;
    out[((size_t)(b * 2048 + t)) * 1024 + hoff + dk] = (__bf16)(ov / ls);
  }
}

extern "C" void kernel_launch(void* const* d_in, const int* in_sizes, int n_in,
                              void* d_out, int out_size, void* d_ws, size_t ws_size,
                              hipStream_t stream) {
  const float* x = (const float*)d_in[0];       // (2,2048,1024) fp32
  const float* w_qkv = (const float*)d_in[1];   // (3072,1024) fp32
  const float* w_o = (const float*)d_in[2];     // (1024,1024) fp32
  float* out = (float*)d_out;                   // (2,2048,1024) fp32

  const int M = 4096;  // B*T
  __bf16* qk = (__bf16*)d_ws;                                    // 4096 x 2048 bf16
  __bf16* vt = (__bf16*)((char*)d_ws + (size_t)M * 2048 * 2);    // 2048 x 2048 bf16 (V^T)
  __bf16* attn = (__bf16*)((char*)d_ws + (size_t)M * 3072 * 2);  // 4096 x 1024 bf16

  // GEMM1: qkv = x @ W_qkv^T ; Q,K -> qk buffer, V -> vt transposed
  gemm_bt<true, true, true><<<(M / 128) * (3072 / 128), 256, 0, stream>>>(
      (const void*)x, w_qkv, (void*)qk, vt, M, 3072, 1024);

  // causal attention (4-way key-split per block, LPT order)
  attn_causal4<<<4096, 256, 0, stream>>>(qk, vt, attn);

  // GEMM2: out = attn @ W_o^T (fp32 out)
  gemm_bt<false, false, false><<<(M / 128) * (1024 / 128), 256, 0, stream>>>(
      (const void*)attn, w_o, (void*)out, nullptr, M, 1024, 1024);
}

// Round 5
// 239.256 us; speedup vs baseline: 1.0963x; 1.0520x over previous
//
#include <hip/hip_runtime.h>
#include <hip/hip_bf16.h>

typedef __bf16 bf16x8 __attribute__((ext_vector_type(8)));
typedef float f32x4 __attribute__((ext_vector_type(4)));
typedef unsigned int u32;
typedef u32 u32x4 __attribute__((ext_vector_type(4)));

#define MFMA(a, b, c) __builtin_amdgcn_mfma_f32_16x16x32_bf16((a), (b), (c), 0, 0, 0)

static __device__ __forceinline__ bf16x8 ld8(const __bf16* p) {
  return *reinterpret_cast<const bf16x8*>(p);
}

// pack two f32 -> bf16x2 in one u32 (compiler fuses to v_cvt_pk_bf16_f32)
static __device__ __forceinline__ u32 pkbf(float a, float b) {
  union { __bf16 h; unsigned short s; } x, y;
  x.h = (__bf16)a; y.h = (__bf16)b;
  return (u32)x.s | ((u32)y.s << 16);
}

// async global->LDS, 16B per lane; l must be the wave-uniform chunk base
typedef unsigned int __attribute__((address_space(1))) gu32_t;
typedef unsigned int __attribute__((address_space(3))) lu32_t;
static __device__ __forceinline__ void gld16(const __bf16* g, __bf16* l) {
  __builtin_amdgcn_global_load_lds((const gu32_t*)(const void*)g,
                                   (lu32_t*)(void*)l, 16, 0, 0);
}

// fp32 -> bf16 conversion for x and W_qkv (exact-fit into d_out region)
__global__ __launch_bounds__(256)
void cvt_f32_bf16(const float* __restrict__ a, __bf16* __restrict__ oa, int na,
                  const float* __restrict__ b, __bf16* __restrict__ ob) {
  const int i = blockIdx.x * 256 + threadIdx.x;  // one 8-elem chunk per thread
  const float* src; __bf16* dst; int e;
  if (i < (na >> 3)) { src = a; dst = oa; e = i << 3; }
  else { src = b; dst = ob; e = (i << 3) - na; }
  f32x4 v0 = *reinterpret_cast<const f32x4*>(src + e);
  f32x4 v1 = *reinterpret_cast<const f32x4*>(src + e + 4);
  bf16x8 o;
#pragma unroll
  for (int j = 0; j < 4; ++j) { o[j] = (__bf16)v0[j]; o[j + 4] = (__bf16)v1[j]; }
  *reinterpret_cast<bf16x8*>(dst + e) = o;
}

// fp32 source staging (GEMM2 B-side): 16 elems/thread with convert
static __device__ __forceinline__ void stage16f(__bf16* __restrict__ dst,
                                                const float* __restrict__ src) {
#pragma unroll
  for (int j = 0; j < 2; ++j) {
    f32x4 a = *reinterpret_cast<const f32x4*>(src + j * 8);
    f32x4 b = *reinterpret_cast<const f32x4*>(src + j * 8 + 4);
    bf16x8 o;
#pragma unroll
    for (int i = 0; i < 4; ++i) { o[i] = (__bf16)a[i]; o[i + 4] = (__bf16)b[i]; }
    *reinterpret_cast<bf16x8*>(dst + j * 8) = o;
  }
}

// C[m][n] = sum_k A[m][k] * W[n][k]  (A @ W^T).
// A bf16 (M x K) staged via global_load_lds(16B). W: bf16 via global_load_lds
// when !B_F32, else fp32 via reg-staging with convert.
// Tile 128x128, BK=32, 4 waves 2x2, wave 64x64 (4x4 frags). LDS linear stride 32.
// SPLIT (GEMM1): cols [0,2048) -> QK buf (stride 2048); [2048,3072) -> VT[b*1024+c-2048][t].
template<bool SPLIT, bool OUT_BF16, bool B_F32>
__global__ __launch_bounds__(256, 2)
void gemm_bt2(const __bf16* __restrict__ A, const void* __restrict__ Wv,
              void* __restrict__ Cv, __bf16* __restrict__ VT,
              int M, int N, int K) {
  __shared__ __bf16 lA[128 * 32];
  __shared__ __bf16 lB[128 * 32];

  const int tid = threadIdx.x;
  const int ntiles = N >> 7;
  const int mt = blockIdx.x / ntiles;
  const int nt = blockIdx.x % ntiles;
  const int m0 = mt << 7, n0 = nt << 7;
  const int lane = tid & 63, w = tid >> 6;
  const int wm = (w >> 1) << 6;
  const int wn = (w & 1) << 6;
  const int fr = lane & 15, fg = lane >> 4;

  f32x4 acc[4][4] = {};

  for (int k0 = 0; k0 < K; k0 += 32) {
    __syncthreads();
    // stage A: 8 chunks of 64x16B; wave w owns chunks 2w, 2w+1
#pragma unroll
    for (int j = 0; j < 2; ++j) {
      const int c = (w << 1) | j;
      const int u = (c << 6) | lane;          // 16B-unit index in tile
      const int row = u >> 2, col = (u & 3) << 3;
      gld16(A + (size_t)(m0 + row) * K + k0 + col, lA + (c << 9));
    }
    if constexpr (B_F32) {
      const int srow = tid >> 1, scol = (tid & 1) << 4;
      stage16f(lB + srow * 32 + scol,
               (const float*)Wv + (size_t)(n0 + srow) * K + k0 + scol);
    } else {
#pragma unroll
      for (int j = 0; j < 2; ++j) {
        const int c = (w << 1) | j;
        const int u = (c << 6) | lane;
        const int row = u >> 2, col = (u & 3) << 3;
        gld16((const __bf16*)Wv + (size_t)(n0 + row) * K + k0 + col, lB + (c << 9));
      }
    }
    __syncthreads();

    bf16x8 af[4], bfr[4];
#pragma unroll
    for (int m = 0; m < 4; ++m)
      af[m] = ld8(lA + (wm + m * 16 + fr) * 32 + fg * 8);
#pragma unroll
    for (int n = 0; n < 4; ++n)
      bfr[n] = ld8(lB + (wn + n * 16 + fr) * 32 + fg * 8);
#pragma unroll
    for (int m = 0; m < 4; ++m)
#pragma unroll
      for (int n = 0; n < 4; ++n)
        acc[m][n] = MFMA(af[m], bfr[n], acc[m][n]);
  }

  // C/D layout: col = lane&15, row = (lane>>4)*4 + reg
#pragma unroll
  for (int m = 0; m < 4; ++m) {
#pragma unroll
    for (int n = 0; n < 4; ++n) {
#pragma unroll
      for (int r = 0; r < 4; ++r) {
        int row = m0 + wm + m * 16 + fg * 4 + r;
        int col = n0 + wn + n * 16 + fr;
        if constexpr (SPLIT) {
          int b = row >> 11, t = row & 2047;
          if (col >= 2048) {
            VT[((size_t)(b << 10) + (col - 2048)) * 2048 + t] = (__bf16)acc[m][n][r];
          } else {
            ((__bf16*)Cv)[(size_t)row * 2048 + col] = (__bf16)acc[m][n][r];
          }
        } else if constexpr (OUT_BF16) {
          ((__bf16*)Cv)[(size_t)row * N + col] = (__bf16)acc[m][n][r];
        } else {
          ((float*)Cv)[(size_t)row * N + col] = acc[m][n][r];
        }
      }
    }
  }
}

// Causal flash attention, intra-block 4-way key-split, ILP-pipelined loads.
// qk: (B*T, 2048) bf16, col = s(0=Q,1=K)*1024 + h*64 + dk.
// vt: (B*1024, 2048) bf16 = V^T per (b,h): row b*1024 + h*64 + dk, col = t.
// Grid: 4096 blocks (one per (qt,bh), LPT) x 256. Waves round-robin kt = w, w+4, ...
// In-register softmax via swapped QK^T; LDS combine of 4 partials.
__global__ __launch_bounds__(256, 4)
void attn_causal5(const __bf16* __restrict__ qk, const __bf16* __restrict__ vt,
                  __bf16* __restrict__ out) {
  constexpr float SC2 = 0.125f * 1.4426950408889634f;  // scale * log2(e)
  constexpr float NEG = -1e30f;

  __shared__ float lO[4][16][65];
  __shared__ float lM[4][16];
  __shared__ float lL[4][16];

  const int tid = threadIdx.x;
  const int lane = tid & 63, w = tid >> 6;
  const int fr = lane & 15, fg = lane >> 4;
  const int blk = blockIdx.x;
  const int qt = 127 - (blk >> 5);   // LPT: longest q-tiles first
  const int bh = blk & 31;
  const int b = bh >> 4, h = bh & 15;
  const int q0 = qt << 4;
  const int hoff = h * 64;
  const size_t qkbase = (size_t)b * (2048 * 2048);
  const __bf16* kb = qk + qkbase + 1024 + hoff;                // K rows, stride 2048
  const __bf16* vtb = vt + (size_t)((b << 10) | hoff) * 2048;  // V^T rows, stride 2048

  bf16x8 qf[2];
#pragma unroll
  for (int c = 0; c < 2; ++c)
    qf[c] = ld8(qk + qkbase + (size_t)(q0 + fr) * 2048 + hoff + c * 32 + fg * 8);

  f32x4 o[4] = {};
  float m = NEG;
  float l = 0.f;

  const int nkt = (q0 + 79) >> 6;

  // prologue: preload this wave's first K tile (always in-bounds: rows < 256)
  bf16x8 kf[2][4];
  {
    const int k0 = w << 6;
#pragma unroll
    for (int n = 0; n < 4; ++n) {
      const __bf16* kp = kb + (size_t)(k0 + n * 16 + fr) * 2048;
#pragma unroll
      for (int c = 0; c < 2; ++c)
        kf[c][n] = ld8(kp + c * 32 + fg * 8);
    }
  }

  for (int kt = w; kt < nkt; kt += 4) {
    const int k0 = kt << 6;

    // issue all V loads first (latency covered by QK + softmax)
    bf16x8 vf[2][4];
#pragma unroll
    for (int n = 0; n < 4; ++n) {
      const __bf16* vp = vtb + (size_t)(n * 16 + fr) * 2048 + k0;
#pragma unroll
      for (int c = 0; c < 2; ++c)
        vf[c][n] = ld8(vp + c * 32 + fg * 8);
    }

    // QK on prefetched K: s[n][r] = S[key=k0+n*16+fg*4+r][q=q0+fr]
    f32x4 s[4] = {};
#pragma unroll
    for (int n = 0; n < 4; ++n)
#pragma unroll
      for (int c = 0; c < 2; ++c)
        s[n] = MFMA(kf[c][n], qf[c], s[n]);

    // prefetch next K (clamped; softmax+PV cover the latency)
    {
      const int k0n = (kt + 4 < nkt) ? ((kt + 4) << 6) : k0;
#pragma unroll
      for (int n = 0; n < 4; ++n) {
        const __bf16* kp = kb + (size_t)(k0n + n * 16 + fr) * 2048;
#pragma unroll
        for (int c = 0; c < 2; ++c)
          kf[c][n] = ld8(kp + c * 32 + fg * 8);
      }
    }

    // scale (log2 domain) + causal mask (only last tile can violate)
    const bool diag = (kt == nkt - 1);
    float sv[4][4];
#pragma unroll
    for (int n = 0; n < 4; ++n)
#pragma unroll
      for (int r = 0; r < 4; ++r) {
        float x = s[n][r] * SC2;
        if (diag && (k0 + n * 16 + fg * 4 + r > q0 + fr)) x = NEG;
        sv[n][r] = x;
      }

    // row max: in-register tree + 2 cross-fg shuffles
    float t0 = fmaxf(fmaxf(sv[0][0], sv[0][1]), fmaxf(sv[0][2], sv[0][3]));
    float t1 = fmaxf(fmaxf(sv[1][0], sv[1][1]), fmaxf(sv[1][2], sv[1][3]));
    float t2 = fmaxf(fmaxf(sv[2][0], sv[2][1]), fmaxf(sv[2][2], sv[2][3]));
    float t3 = fmaxf(fmaxf(sv[3][0], sv[3][1]), fmaxf(sv[3][2], sv[3][3]));
    float rm = fmaxf(fmaxf(t0, t1), fmaxf(t2, t3));
    rm = fmaxf(rm, __shfl_xor(rm, 16));
    rm = fmaxf(rm, __shfl_xor(rm, 32));

    // defer-max (T13)
    if (!__all(rm <= m + 16.f)) {
      float mnew = fmaxf(m, rm);
      float alpha = __builtin_exp2f(m - mnew);
      m = mnew;
      l *= alpha;
      float ao[4];
#pragma unroll
      for (int r = 0; r < 4; ++r)
        ao[r] = __shfl(alpha, fg * 4 + r);
#pragma unroll
      for (int n = 0; n < 4; ++n)
#pragma unroll
        for (int r = 0; r < 4; ++r)
          o[n][r] *= ao[r];
    }

    // P = exp2(sv - m)
    float p[4][4];
#pragma unroll
    for (int n = 0; n < 4; ++n)
#pragma unroll
      for (int r = 0; r < 4; ++r)
        p[n][r] = __builtin_exp2f(sv[n][r] - m);

    // row sum: tree + 2 shuffles
    float u0 = (p[0][0] + p[0][1]) + (p[0][2] + p[0][3]);
    float u1 = (p[1][0] + p[1][1]) + (p[1][2] + p[1][3]);
    float u2 = (p[2][0] + p[2][1]) + (p[2][2] + p[2][3]);
    float u3 = (p[3][0] + p[3][1]) + (p[3][2] + p[3][3]);
    float rs = (u0 + u1) + (u2 + u3);
    rs += __shfl_xor(rs, 16);
    rs += __shfl_xor(rs, 32);
    l += rs;

    // pack P to bf16 pairs
    u32 wpk[4][2];
#pragma unroll
    for (int n = 0; n < 4; ++n) {
      wpk[n][0] = pkbf(p[n][0], p[n][1]);
      wpk[n][1] = pkbf(p[n][2], p[n][3]);
    }

    // redistribute P^T -> PV A-fragments (8 bpermutes; bijective instances)
    u32 rcv[2][2][2];
#pragma unroll
    for (int e = 0; e < 2; ++e) {
      const int src = fr + ((((fg & 1) << 1) | ((fg >> 1) ^ e)) << 4);
      const bool tsel = ((fg & 1) ^ e) != 0;
#pragma unroll
      for (int c = 0; c < 2; ++c)
#pragma unroll
        for (int hh = 0; hh < 2; ++hh) {
          u32 v = tsel ? wpk[(c << 1) | 1][hh] : wpk[(c << 1) | 0][hh];
          rcv[e][c][hh] = (u32)__shfl((int)v, src);
        }
    }
    const bool hi = (fg >> 1) != 0;
    u32x4 w0, w1;
#pragma unroll
    for (int a = 0; a < 2; ++a)
#pragma unroll
      for (int hh = 0; hh < 2; ++hh) {
        w0[2 * a + hh] = hi ? rcv[a ^ 1][0][hh] : rcv[a][0][hh];
        w1[2 * a + hh] = hi ? rcv[a ^ 1][1][hh] : rcv[a][1][hh];
      }
    bf16x8 pa[2];
    pa[0] = __builtin_bit_cast(bf16x8, w0);
    pa[1] = __builtin_bit_cast(bf16x8, w1);

    // O += P V
#pragma unroll
    for (int c = 0; c < 2; ++c)
#pragma unroll
      for (int n = 0; n < 4; ++n)
        o[n] = MFMA(pa[c], vf[c][n], o[n]);
  }

  // ---- write partials ----
  if (fg == 0) { lM[w][fr] = m; lL[w][fr] = l; }
#pragma unroll
  for (int n = 0; n < 4; ++n)
#pragma unroll
    for (int r = 0; r < 4; ++r)
      lO[w][fg * 4 + r][n * 16 + fr] = o[n][r];
  __syncthreads();

  // ---- combine: lane (fg,fr) of wave w -> q = fg*4+r, dk = w*16+fr ----
#pragma unroll
  for (int r = 0; r < 4; ++r) {
    const int q = fg * 4 + r;
    float m0 = lM[0][q], m1 = lM[1][q], m2 = lM[2][q], m3 = lM[3][q];
    float ms = fmaxf(fmaxf(m0, m1), fmaxf(m2, m3));
    float w0 = __builtin_exp2f(m0 - ms);
    float w1 = __builtin_exp2f(m1 - ms);
    float w2 = __builtin_exp2f(m2 - ms);
    float w3 = __builtin_exp2f(m3 - ms);
    float ls = w0 * lL[0][q] + w1 * lL[1][q] + w2 * lL[2][q] + w3 * lL[3][q];
    const int dk = w * 16 + fr;
    float ov = w0 * lO[0][q][dk] + w1 * lO[1][q][dk]
             + w2 * lO[2][q][dk] + w3 * lO[3][q][dk];
    const int t = q0 + q;
    out[((size_t)(b * 2048 + t)) * 1024 + hoff + dk] = (__bf16)(ov / ls);
  }
}

extern "C" void kernel_launch(void* const* d_in, const int* in_sizes, int n_in,
                              void* d_out, int out_size, void* d_ws, size_t ws_size,
                              hipStream_t stream) {
  const float* x = (const float*)d_in[0];       // (2,2048,1024) fp32
  const float* w_qkv = (const float*)d_in[1];   // (3072,1024) fp32
  const float* w_o = (const float*)d_in[2];     // (1024,1024) fp32
  float* out = (float*)d_out;                   // (2,2048,1024) fp32

  const int M = 4096;  // B*T
  __bf16* qk = (__bf16*)d_ws;                                    // 4096 x 2048 bf16 (16MB)
  __bf16* vt = (__bf16*)((char*)d_ws + (size_t)M * 2048 * 2);    // 2048 x 2048 bf16 (8MB)
  __bf16* attn = (__bf16*)((char*)d_ws + (size_t)M * 3072 * 2);  // 4096 x 1024 bf16 (8MB)

  // bf16 copies of x and W_qkv live in d_out (dead before GEMM2 writes it):
  // xb 8.39MB + wqb 6.29MB = 14.68MB <= 16.78MB
  __bf16* xb = (__bf16*)d_out;
  __bf16* wqb = xb + 4194304;
  const int NX = 4194304;  // x elems

  // convert: 3584 blocks x 256 thr x 8 elems = 7,340,032 elems (exact)
  cvt_f32_bf16<<<3584, 256, 0, stream>>>(x, xb, NX, w_qkv, wqb);

  // GEMM1: qkv = x @ W_qkv^T ; Q,K -> qk, V -> vt transposed (both operands bf16)
  gemm_bt2<true, true, false><<<(M / 128) * (3072 / 128), 256, 0, stream>>>(
      xb, (const void*)wqb, (void*)qk, vt, M, 3072, 1024);

  // causal attention
  attn_causal5<<<4096, 256, 0, stream>>>(qk, vt, attn);

  // GEMM2: out = attn @ W_o^T (A bf16 via gload_lds, B fp32 reg-staged)
  gemm_bt2<false, false, true><<<(M / 128) * (1024 / 128), 256, 0, stream>>>(
      attn, (const void*)w_o, (void*)out, nullptr, M, 1024, 1024);
}

// Round 6
// 137.033 us; speedup vs baseline: 1.9141x; 1.7460x over previous
//
#include <hip/hip_runtime.h>
#include <hip/hip_bf16.h>

typedef __bf16 bf16x8 __attribute__((ext_vector_type(8)));
typedef float f32x4 __attribute__((ext_vector_type(4)));
typedef unsigned int u32;
typedef u32 u32x4 __attribute__((ext_vector_type(4)));

#define MFMA(a, b, c) __builtin_amdgcn_mfma_f32_16x16x32_bf16((a), (b), (c), 0, 0, 0)

static __device__ __forceinline__ bf16x8 ld8(const __bf16* p) {
  return *reinterpret_cast<const bf16x8*>(p);
}

// pack two f32 -> bf16x2 in one u32 (compiler fuses to v_cvt_pk_bf16_f32)
static __device__ __forceinline__ u32 pkbf(float a, float b) {
  union { __bf16 h; unsigned short s; } x, y;
  x.h = (__bf16)a; y.h = (__bf16)b;
  return (u32)x.s | ((u32)y.s << 16);
}

// async global->LDS, 16B per lane; LDS dest is wave-uniform base + lane*16
typedef unsigned int __attribute__((address_space(1))) gu32_t;
typedef unsigned int __attribute__((address_space(3))) lu32_t;
static __device__ __forceinline__ void gld16(const __bf16* g, __bf16* l) {
  __builtin_amdgcn_global_load_lds((const gu32_t*)(const void*)g,
                                   (lu32_t*)(void*)l, 16, 0, 0);
}

// fp32 -> bf16 conversion for x and W_qkv (exact-fit into d_out region)
__global__ __launch_bounds__(256)
void cvt_f32_bf16(const float* __restrict__ a, __bf16* __restrict__ oa, int na,
                  const float* __restrict__ b, __bf16* __restrict__ ob) {
  const int i = blockIdx.x * 256 + threadIdx.x;  // one 8-elem chunk per thread
  const float* src; __bf16* dst; int e;
  if (i < (na >> 3)) { src = a; dst = oa; e = i << 3; }
  else { src = b; dst = ob; e = (i << 3) - na; }
  f32x4 v0 = *reinterpret_cast<const f32x4*>(src + e);
  f32x4 v1 = *reinterpret_cast<const f32x4*>(src + e + 4);
  bf16x8 o;
#pragma unroll
  for (int j = 0; j < 4; ++j) { o[j] = (__bf16)v0[j]; o[j + 4] = (__bf16)v1[j]; }
  *reinterpret_cast<bf16x8*>(dst + e) = o;
}

// fp32 source staging (GEMM2 B-side): 16 elems/thread with convert
static __device__ __forceinline__ void stage16f(__bf16* __restrict__ dst,
                                                const float* __restrict__ src) {
#pragma unroll
  for (int j = 0; j < 2; ++j) {
    f32x4 a = *reinterpret_cast<const f32x4*>(src + j * 8);
    f32x4 b = *reinterpret_cast<const f32x4*>(src + j * 8 + 4);
    bf16x8 o;
#pragma unroll
    for (int i = 0; i < 4; ++i) { o[i] = (__bf16)a[i]; o[i + 4] = (__bf16)b[i]; }
    *reinterpret_cast<bf16x8*>(dst + j * 8) = o;
  }
}

// C[m][n] = sum_k A[m][k] * W[n][k]  (A @ W^T).
// A bf16 staged via global_load_lds(16B). W: bf16 via global_load_lds when
// !B_F32, else fp32 via reg-staging with convert.
// Tile 128x128, BK=32, 4 waves 2x2, wave 64x64 (4x4 frags). LDS linear stride 32.
// SPLIT (GEMM1): cols [0,2048) -> QK buf (stride 2048); [2048,3072) -> VT[b*1024+c-2048][t].
template<bool SPLIT, bool OUT_BF16, bool B_F32>
__global__ __launch_bounds__(256, 2)
void gemm_bt2(const __bf16* __restrict__ A, const void* __restrict__ Wv,
              void* __restrict__ Cv, __bf16* __restrict__ VT,
              int M, int N, int K) {
  __shared__ __bf16 lA[128 * 32];
  __shared__ __bf16 lB[128 * 32];

  const int tid = threadIdx.x;
  const int ntiles = N >> 7;
  const int mt = blockIdx.x / ntiles;
  const int nt = blockIdx.x % ntiles;
  const int m0 = mt << 7, n0 = nt << 7;
  const int lane = tid & 63, w = tid >> 6;
  const int wm = (w >> 1) << 6;
  const int wn = (w & 1) << 6;
  const int fr = lane & 15, fg = lane >> 4;

  f32x4 acc[4][4] = {};

  for (int k0 = 0; k0 < K; k0 += 32) {
    __syncthreads();
#pragma unroll
    for (int j = 0; j < 2; ++j) {
      const int c = (w << 1) | j;
      const int u = (c << 6) | lane;          // 16B-unit index in tile
      const int row = u >> 2, col = (u & 3) << 3;
      gld16(A + (size_t)(m0 + row) * K + k0 + col, lA + (c << 9));
    }
    if constexpr (B_F32) {
      const int srow = tid >> 1, scol = (tid & 1) << 4;
      stage16f(lB + srow * 32 + scol,
               (const float*)Wv + (size_t)(n0 + srow) * K + k0 + scol);
    } else {
#pragma unroll
      for (int j = 0; j < 2; ++j) {
        const int c = (w << 1) | j;
        const int u = (c << 6) | lane;
        const int row = u >> 2, col = (u & 3) << 3;
        gld16((const __bf16*)Wv + (size_t)(n0 + row) * K + k0 + col, lB + (c << 9));
      }
    }
    __syncthreads();

    bf16x8 af[4], bfr[4];
#pragma unroll
    for (int m = 0; m < 4; ++m)
      af[m] = ld8(lA + (wm + m * 16 + fr) * 32 + fg * 8);
#pragma unroll
    for (int n = 0; n < 4; ++n)
      bfr[n] = ld8(lB + (wn + n * 16 + fr) * 32 + fg * 8);
#pragma unroll
    for (int m = 0; m < 4; ++m)
#pragma unroll
      for (int n = 0; n < 4; ++n)
        acc[m][n] = MFMA(af[m], bfr[n], acc[m][n]);
  }

  // C/D layout: col = lane&15, row = (lane>>4)*4 + reg
#pragma unroll
  for (int m = 0; m < 4; ++m) {
#pragma unroll
    for (int n = 0; n < 4; ++n) {
#pragma unroll
      for (int r = 0; r < 4; ++r) {
        int row = m0 + wm + m * 16 + fg * 4 + r;
        int col = n0 + wn + n * 16 + fr;
        if constexpr (SPLIT) {
          int b = row >> 11, t = row & 2047;
          if (col >= 2048) {
            VT[((size_t)(b << 10) + (col - 2048)) * 2048 + t] = (__bf16)acc[m][n][r];
          } else {
            ((__bf16*)Cv)[(size_t)row * 2048 + col] = (__bf16)acc[m][n][r];
          }
        } else if constexpr (OUT_BF16) {
          ((__bf16*)Cv)[(size_t)row * N + col] = (__bf16)acc[m][n][r];
        } else {
          ((float*)Cv)[(size_t)row * N + col] = acc[m][n][r];
        }
      }
    }
  }
}

// FA2-style causal flash attention.
// qk: (B*T, 2048) bf16, col = s(0=Q,1=K)*1024 + h*64 + dk.
// vt: (B*1024, 2048) bf16 = V^T per (b,h): row b*1024 + h*64 + dk, col = t.
// Grid: 1024 blocks x 256. Block = (qb, bh): 64 q-rows, wave w owns rows
// [qb*64 + w*16, +16). All waves iterate the same key tiles (kt = 0..qb);
// K/V^T tiles (64x64 bf16 each) double-buffered in LDS via global_load_lds,
// chunk-XOR swizzled (chunk ^= row&7; pre-swizzled global source, linear LDS
// dest, swizzled ds_read). One __syncthreads per tile; STAGE(next) issued
// before compute so loads fly under it.
// In-register softmax via swapped QK^T (S^T = mfma(K, Q)): C col = lane&15 =
// q-row, C row = fg*4+r = key-sub; per-lane stats at q-row = fr.
// XCD-swizzle: xcd = blk&7 gets bh in {4*xcd..4*xcd+3} (2MB KV per XCD L2).
__global__ __launch_bounds__(256, 4)
void attn_causal6(const __bf16* __restrict__ qk, const __bf16* __restrict__ vt,
                  __bf16* __restrict__ out) {
  constexpr float SC2 = 0.125f * 1.4426950408889634f;  // scale * log2(e)
  constexpr float NEG = -1e30f;

  __shared__ __bf16 lK[2][4096];  // [buf][key(64) x dkchunk(8) x 8], 8KB each
  __shared__ __bf16 lV[2][4096];  // [buf][dk(64) x keychunk(8) x 8]

  const int tid = threadIdx.x;
  const int lane = tid & 63, w = tid >> 6;
  const int fr = lane & 15, fg = lane >> 4;
  const int blk = blockIdx.x;
  const int j = blk >> 3;
  const int bh = ((blk & 7) << 2) | (j & 3);  // XCD-local bh group
  const int qb = 31 - (j >> 2);               // LPT: longest first
  const int b = bh >> 4, h = bh & 15;
  const int q0w = (qb << 6) + (w << 4);       // this wave's q base
  const int hoff = h * 64;
  const size_t qkbase = (size_t)b * (2048 * 2048);
  const __bf16* kb = qk + qkbase + 1024 + hoff;                // K rows, stride 2048
  const __bf16* vtb = vt + (size_t)((b << 10) | hoff) * 2048;  // V^T rows, stride 2048

  // Q fragments (B-operand): col = fr = q-row, k = c*32 + fg*8 + i
  bf16x8 qf[2];
#pragma unroll
  for (int c = 0; c < 2; ++c)
    qf[c] = ld8(qk + qkbase + (size_t)(q0w + fr) * 2048 + hoff + c * 32 + fg * 8);

  f32x4 o[4] = {};
  float m = NEG;
  float l = 0.f;

  // stage K & V^T tiles for key base k0s into buffer bf.
  // chunk q = 2w+j; 16B-unit v = q*64+lane -> LDS byte v*16 (linear);
  // global source chunk = (v&7) ^ (row&7)  [pre-swizzle]
#define STAGE(bf, k0s)                                                        \
  do {                                                                        \
    _Pragma("unroll")                                                         \
    for (int jj = 0; jj < 2; ++jj) {                                          \
      const int q = (w << 1) | jj;                                            \
      const int v = (q << 6) | lane;                                          \
      const int row = v >> 3;                                                 \
      const int cc = (v & 7) ^ (row & 7);                                     \
      gld16(kb + (size_t)((k0s) + row) * 2048 + (cc << 3), &lK[bf][q << 9]);  \
      gld16(vtb + (size_t)row * 2048 + (k0s) + (cc << 3), &lV[bf][q << 9]);   \
    }                                                                         \
  } while (0)

  int buf = 0;
  STAGE(0, 0);
  __syncthreads();

  for (int kt = 0; kt <= qb; ++kt) {
    const int k0 = kt << 6;
    if (kt < qb) STAGE(buf ^ 1, k0 + 64);  // prefetch next tile (other buffer)

    // QK on LDS K: s[n][r] = S[key=k0+n*16+fg*4+r][q=q0w+fr] (pre-scale)
    f32x4 s[4] = {};
#pragma unroll
    for (int c = 0; c < 2; ++c) {
      bf16x8 kfc[4];
#pragma unroll
      for (int n = 0; n < 4; ++n) {
        const int row = n * 16 + fr;
        const int sc = ((c << 2) | fg) ^ (row & 7);
        kfc[n] = ld8(&lK[buf][(row << 6) + (sc << 3)]);
      }
#pragma unroll
      for (int n = 0; n < 4; ++n)
        s[n] = MFMA(kfc[n], qf[c], s[n]);
    }

    // scale (log2 domain) + causal mask (only diag tile kt==qb can violate)
    const bool diag = (kt == qb);
    float sv[4][4];
#pragma unroll
    for (int n = 0; n < 4; ++n)
#pragma unroll
      for (int r = 0; r < 4; ++r) {
        float x = s[n][r] * SC2;
        if (diag && (k0 + n * 16 + fg * 4 + r > q0w + fr)) x = NEG;
        sv[n][r] = x;
      }

    // row max: in-register tree + 2 cross-fg shuffles
    float t0 = fmaxf(fmaxf(sv[0][0], sv[0][1]), fmaxf(sv[0][2], sv[0][3]));
    float t1 = fmaxf(fmaxf(sv[1][0], sv[1][1]), fmaxf(sv[1][2], sv[1][3]));
    float t2 = fmaxf(fmaxf(sv[2][0], sv[2][1]), fmaxf(sv[2][2], sv[2][3]));
    float t3 = fmaxf(fmaxf(sv[3][0], sv[3][1]), fmaxf(sv[3][2], sv[3][3]));
    float rm = fmaxf(fmaxf(t0, t1), fmaxf(t2, t3));
    rm = fmaxf(rm, __shfl_xor(rm, 16));
    rm = fmaxf(rm, __shfl_xor(rm, 32));

    // defer-max (T13)
    if (!__all(rm <= m + 16.f)) {
      float mnew = fmaxf(m, rm);
      float alpha = __builtin_exp2f(m - mnew);
      m = mnew;
      l *= alpha;
      float ao[4];
#pragma unroll
      for (int r = 0; r < 4; ++r)
        ao[r] = __shfl(alpha, fg * 4 + r);
#pragma unroll
      for (int n = 0; n < 4; ++n)
#pragma unroll
        for (int r = 0; r < 4; ++r)
          o[n][r] *= ao[r];
    }

    // P = exp2(sv - m)
    float p[4][4];
#pragma unroll
    for (int n = 0; n < 4; ++n)
#pragma unroll
      for (int r = 0; r < 4; ++r)
        p[n][r] = __builtin_exp2f(sv[n][r] - m);

    // row sum: tree + 2 shuffles
    float u0 = (p[0][0] + p[0][1]) + (p[0][2] + p[0][3]);
    float u1 = (p[1][0] + p[1][1]) + (p[1][2] + p[1][3]);
    float u2 = (p[2][0] + p[2][1]) + (p[2][2] + p[2][3]);
    float u3 = (p[3][0] + p[3][1]) + (p[3][2] + p[3][3]);
    float rs = (u0 + u1) + (u2 + u3);
    rs += __shfl_xor(rs, 16);
    rs += __shfl_xor(rs, 32);
    l += rs;

    // pack P to bf16 pairs
    u32 wpk[4][2];
#pragma unroll
    for (int n = 0; n < 4; ++n) {
      wpk[n][0] = pkbf(p[n][0], p[n][1]);
      wpk[n][1] = pkbf(p[n][2], p[n][3]);
    }

    // redistribute P^T -> PV A-fragments (8 bpermutes; bijective instances)
    u32 rcv[2][2][2];
#pragma unroll
    for (int e = 0; e < 2; ++e) {
      const int src = fr + ((((fg & 1) << 1) | ((fg >> 1) ^ e)) << 4);
      const bool tsel = ((fg & 1) ^ e) != 0;
#pragma unroll
      for (int c = 0; c < 2; ++c)
#pragma unroll
        for (int hh = 0; hh < 2; ++hh) {
          u32 v = tsel ? wpk[(c << 1) | 1][hh] : wpk[(c << 1) | 0][hh];
          rcv[e][c][hh] = (u32)__shfl((int)v, src);
        }
    }
    const bool hi = (fg >> 1) != 0;
    u32x4 w0, w1;
#pragma unroll
    for (int a = 0; a < 2; ++a)
#pragma unroll
      for (int hh = 0; hh < 2; ++hh) {
        w0[2 * a + hh] = hi ? rcv[a ^ 1][0][hh] : rcv[a][0][hh];
        w1[2 * a + hh] = hi ? rcv[a ^ 1][1][hh] : rcv[a][1][hh];
      }
    bf16x8 pa[2];
    pa[0] = __builtin_bit_cast(bf16x8, w0);
    pa[1] = __builtin_bit_cast(bf16x8, w1);

    // O += P V from LDS V^T: B-frag row = dk = n*16+fr, key chunk = c*4+fg
#pragma unroll
    for (int c = 0; c < 2; ++c) {
      bf16x8 vfc[4];
#pragma unroll
      for (int n = 0; n < 4; ++n) {
        const int row = n * 16 + fr;
        const int sc = ((c << 2) | fg) ^ (row & 7);
        vfc[n] = ld8(&lV[buf][(row << 6) + (sc << 3)]);
      }
#pragma unroll
      for (int n = 0; n < 4; ++n)
        o[n] = MFMA(pa[c], vfc[n], o[n]);
    }

    __syncthreads();  // drains vmcnt (STAGE done) + all waves done reading buf
    buf ^= 1;
  }
#undef STAGE

  // normalize: linv per q-row fr -> transpose to O rows via 4 bpermutes
  float linv = 1.f / l;
  float lo[4];
#pragma unroll
  for (int r = 0; r < 4; ++r)
    lo[r] = __shfl(linv, fg * 4 + r);
#pragma unroll
  for (int n = 0; n < 4; ++n)
#pragma unroll
    for (int r = 0; r < 4; ++r) {
      int t = q0w + fg * 4 + r;
      out[((size_t)(b * 2048 + t)) * 1024 + hoff + n * 16 + fr] = (__bf16)(o[n][r] * lo[r]);
    }
}

extern "C" void kernel_launch(void* const* d_in, const int* in_sizes, int n_in,
                              void* d_out, int out_size, void* d_ws, size_t ws_size,
                              hipStream_t stream) {
  const float* x = (const float*)d_in[0];       // (2,2048,1024) fp32
  const float* w_qkv = (const float*)d_in[1];   // (3072,1024) fp32
  const float* w_o = (const float*)d_in[2];     // (1024,1024) fp32
  float* out = (float*)d_out;                   // (2,2048,1024) fp32

  const int M = 4096;  // B*T
  __bf16* qk = (__bf16*)d_ws;                                    // 4096 x 2048 bf16 (16MB)
  __bf16* vt = (__bf16*)((char*)d_ws + (size_t)M * 2048 * 2);    // 2048 x 2048 bf16 (8MB)
  __bf16* attn = (__bf16*)((char*)d_ws + (size_t)M * 3072 * 2);  // 4096 x 1024 bf16 (8MB)

  // bf16 copies of x and W_qkv live in d_out (dead before GEMM2 writes it):
  // xb 8.39MB + wqb 6.29MB = 14.68MB <= 16.78MB
  __bf16* xb = (__bf16*)d_out;
  __bf16* wqb = xb + 4194304;
  const int NX = 4194304;  // x elems

  // convert: 3584 blocks x 256 thr x 8 elems = 7,340,032 elems (exact)
  cvt_f32_bf16<<<3584, 256, 0, stream>>>(x, xb, NX, w_qkv, wqb);

  // GEMM1: qkv = x @ W_qkv^T ; Q,K -> qk, V -> vt transposed (both operands bf16)
  gemm_bt2<true, true, false><<<(M / 128) * (3072 / 128), 256, 0, stream>>>(
      xb, (const void*)wqb, (void*)qk, vt, M, 3072, 1024);

  // causal attention (FA2 structure, LDS-staged K/V, double-buffered)
  attn_causal6<<<1024, 256, 0, stream>>>(qk, vt, attn);

  // GEMM2: out = attn @ W_o^T (A bf16 via gload_lds, B fp32 reg-staged)
  gemm_bt2<false, false, true><<<(M / 128) * (1024 / 128), 256, 0, stream>>>(
      attn, (const void*)w_o, (void*)out, nullptr, M, 1024, 1024);
}

// Round 7
// 127.139 us; speedup vs baseline: 2.0631x; 1.0778x over previous
//
#include <hip/hip_runtime.h>
#include <hip/hip_bf16.h>

typedef __bf16 bf16x8 __attribute__((ext_vector_type(8)));
typedef float f32x4 __attribute__((ext_vector_type(4)));
typedef unsigned int u32;
typedef u32 u32x4 __attribute__((ext_vector_type(4)));

#define MFMA(a, b, c) __builtin_amdgcn_mfma_f32_16x16x32_bf16((a), (b), (c), 0, 0, 0)

static __device__ __forceinline__ bf16x8 ld8(const __bf16* p) {
  return *reinterpret_cast<const bf16x8*>(p);
}

// pack two f32 -> bf16x2 in one u32 (compiler fuses to v_cvt_pk_bf16_f32)
static __device__ __forceinline__ u32 pkbf(float a, float b) {
  union { __bf16 h; unsigned short s; } x, y;
  x.h = (__bf16)a; y.h = (__bf16)b;
  return (u32)x.s | ((u32)y.s << 16);
}

// async global->LDS, 16B per lane; LDS dest is wave-uniform base + lane*16
typedef unsigned int __attribute__((address_space(1))) gu32_t;
typedef unsigned int __attribute__((address_space(3))) lu32_t;
static __device__ __forceinline__ void gld16(const __bf16* g, __bf16* l) {
  __builtin_amdgcn_global_load_lds((const gu32_t*)(const void*)g,
                                   (lu32_t*)(void*)l, 16, 0, 0);
}

// fp32 -> bf16 conversion for x and W_qkv (exact-fit into d_out region)
__global__ __launch_bounds__(256)
void cvt_f32_bf16(const float* __restrict__ a, __bf16* __restrict__ oa, int na,
                  const float* __restrict__ b, __bf16* __restrict__ ob) {
  const int i = blockIdx.x * 256 + threadIdx.x;  // one 8-elem chunk per thread
  const float* src; __bf16* dst; int e;
  if (i < (na >> 3)) { src = a; dst = oa; e = i << 3; }
  else { src = b; dst = ob; e = (i << 3) - na; }
  f32x4 v0 = *reinterpret_cast<const f32x4*>(src + e);
  f32x4 v1 = *reinterpret_cast<const f32x4*>(src + e + 4);
  bf16x8 o;
#pragma unroll
  for (int j = 0; j < 4; ++j) { o[j] = (__bf16)v0[j]; o[j + 4] = (__bf16)v1[j]; }
  *reinterpret_cast<bf16x8*>(dst + e) = o;
}

// 8 fp32 -> 8 bf16 LDS write (16B)
static __device__ __forceinline__ void stage8f(__bf16* __restrict__ dst,
                                               const float* __restrict__ src) {
  f32x4 a = *reinterpret_cast<const f32x4*>(src);
  f32x4 b = *reinterpret_cast<const f32x4*>(src + 4);
  bf16x8 o;
#pragma unroll
  for (int i = 0; i < 4; ++i) { o[i] = (__bf16)a[i]; o[i + 4] = (__bf16)b[i]; }
  *reinterpret_cast<bf16x8*>(dst) = o;
}

// C[m][n] = sum_k A[m][k] * W[n][k]  (A @ W^T).  BM=128, BK=64, BN template.
// A bf16 via global_load_lds(16B), pre-swizzled source (chunk ^= row&7).
// W: bf16 via gld16 (same swizzle) or fp32 via reg-stage + swizzled ds_write.
// 4 waves 2x2; wave tile 64 x BN/2. SPLIT (GEMM1): Q cols scaled by SC2Q;
// cols [0,2048) -> QK buf; [2048,3072) -> VT[b*1024+col-2048][t].
template<int BN, bool SPLIT, bool OUT_BF16, bool B_F32>
__global__ __launch_bounds__(256, 2)
void gemm3(const __bf16* __restrict__ A, const void* __restrict__ Wv,
           void* __restrict__ Cv, __bf16* __restrict__ VT,
           int M, int N, int K) {
  constexpr int NF = BN / 32;  // B frags per wave per kc
  constexpr float SC2Q = 0.125f * 1.4426950408889634f;
  __shared__ __bf16 lA[128 * 64];
  __shared__ __bf16 lB[BN * 64];

  const int tid = threadIdx.x;
  const int ntiles = N / BN;
  const int mt = blockIdx.x / ntiles;
  const int nt = blockIdx.x % ntiles;
  const int m0 = mt << 7, n0 = nt * BN;
  const int lane = tid & 63, w = tid >> 6;
  const int wm = (w >> 1) << 6;
  const int wn = (w & 1) * (BN / 2);
  const int fr = lane & 15, fg = lane >> 4;

  f32x4 acc[4][NF] = {};

  for (int k0 = 0; k0 < K; k0 += 64) {
    __syncthreads();
    // stage A: 1024 16B-units, 16 wave-chunks; wave w -> chunks 4w..4w+3
#pragma unroll
    for (int jj = 0; jj < 4; ++jj) {
      const int q = (w << 2) | jj;
      const int v = (q << 6) | lane;
      const int row = v >> 3;
      const int cc = (v & 7) ^ (row & 7);
      gld16(A + (size_t)(m0 + row) * K + k0 + (cc << 3), lA + (q << 9));
    }
    if constexpr (B_F32) {
#pragma unroll
      for (int hh = 0; hh < BN / 64; ++hh) {
        const int row = (tid >> 2) + (hh << 6);
        const int c0 = (tid & 3) << 1;
        const float* src = (const float*)Wv + (size_t)(n0 + row) * K + k0 + (c0 << 3);
#pragma unroll
        for (int cg = 0; cg < 2; ++cg)
          stage8f(lB + (row << 6) + (((c0 + cg) ^ (row & 7)) << 3), src + (cg << 3));
      }
    } else {
#pragma unroll
      for (int jj = 0; jj < NF; ++jj) {
        const int q = w * NF + jj;
        const int v = (q << 6) | lane;
        const int row = v >> 3;
        const int cc = (v & 7) ^ (row & 7);
        gld16((const __bf16*)Wv + (size_t)(n0 + row) * K + k0 + (cc << 3), lB + (q << 9));
      }
    }
    __syncthreads();

    bf16x8 af[2][4], bfr[2][NF];
#pragma unroll
    for (int kc = 0; kc < 2; ++kc) {
#pragma unroll
      for (int m = 0; m < 4; ++m) {
        const int row = wm + m * 16 + fr;
        af[kc][m] = ld8(lA + (row << 6) + ((((kc << 2) | fg) ^ (row & 7)) << 3));
      }
#pragma unroll
      for (int n = 0; n < NF; ++n) {
        const int row = wn + n * 16 + fr;
        bfr[kc][n] = ld8(lB + (row << 6) + ((((kc << 2) | fg) ^ (row & 7)) << 3));
      }
    }
#pragma unroll
    for (int kc = 0; kc < 2; ++kc)
#pragma unroll
      for (int m = 0; m < 4; ++m)
#pragma unroll
        for (int n = 0; n < NF; ++n)
          acc[m][n] = MFMA(af[kc][m], bfr[kc][n], acc[m][n]);
  }

  // C/D layout: col = lane&15, row = (lane>>4)*4 + reg
#pragma unroll
  for (int m = 0; m < 4; ++m) {
#pragma unroll
    for (int n = 0; n < NF; ++n) {
#pragma unroll
      for (int r = 0; r < 4; ++r) {
        int row = m0 + wm + m * 16 + fg * 4 + r;
        int col = n0 + wn + n * 16 + fr;
        float v = acc[m][n][r];
        if constexpr (SPLIT) {
          int b = row >> 11, t = row & 2047;
          if (col >= 2048) {
            VT[((size_t)(b << 10) + (col - 2048)) * 2048 + t] = (__bf16)v;
          } else {
            if (col < 1024) v *= SC2Q;  // pre-scale Q for attention
            ((__bf16*)Cv)[(size_t)row * 2048 + col] = (__bf16)v;
          }
        } else if constexpr (OUT_BF16) {
          ((__bf16*)Cv)[(size_t)row * N + col] = (__bf16)v;
        } else {
          ((float*)Cv)[(size_t)row * N + col] = v;
        }
      }
    }
  }
}

// One online-softmax step for a 64-key tile held as S^T fragments.
// s[n][r] = S[key=k0+n*16+fg*4+r][q=q0wt+fr] (already scaled, log2 domain).
// Updates (o, m, l); produces PV A-fragments pa[2].
static __device__ __forceinline__ void softmax_step(
    f32x4 (&s)[4], f32x4 (&o)[4], float& m, float& l, bf16x8 (&pa)[2],
    bool diag, int q0wt, int k0, int fg, int fr) {
  constexpr float NEG = -1e30f;
  float sv[4][4];
#pragma unroll
  for (int n = 0; n < 4; ++n)
#pragma unroll
    for (int r = 0; r < 4; ++r) {
      float x = s[n][r];
      if (diag && (k0 + n * 16 + fg * 4 + r > q0wt + fr)) x = NEG;
      sv[n][r] = x;
    }

  float t0 = fmaxf(fmaxf(sv[0][0], sv[0][1]), fmaxf(sv[0][2], sv[0][3]));
  float t1 = fmaxf(fmaxf(sv[1][0], sv[1][1]), fmaxf(sv[1][2], sv[1][3]));
  float t2 = fmaxf(fmaxf(sv[2][0], sv[2][1]), fmaxf(sv[2][2], sv[2][3]));
  float t3 = fmaxf(fmaxf(sv[3][0], sv[3][1]), fmaxf(sv[3][2], sv[3][3]));
  float rm = fmaxf(fmaxf(t0, t1), fmaxf(t2, t3));
  rm = fmaxf(rm, __shfl_xor(rm, 16));
  rm = fmaxf(rm, __shfl_xor(rm, 32));

  // defer-max (T13): rescale only when tile max pushes past m+16
  if (!__all(rm <= m + 16.f)) {
    float mnew = fmaxf(m, rm);
    float alpha = __builtin_exp2f(m - mnew);
    m = mnew;
    l *= alpha;
    float ao[4];
#pragma unroll
    for (int r = 0; r < 4; ++r)
      ao[r] = __shfl(alpha, fg * 4 + r);
#pragma unroll
    for (int n = 0; n < 4; ++n)
#pragma unroll
      for (int r = 0; r < 4; ++r)
        o[n][r] *= ao[r];
  }

  float p[4][4];
#pragma unroll
  for (int n = 0; n < 4; ++n)
#pragma unroll
    for (int r = 0; r < 4; ++r)
      p[n][r] = __builtin_exp2f(sv[n][r] - m);

  float u0 = (p[0][0] + p[0][1]) + (p[0][2] + p[0][3]);
  float u1 = (p[1][0] + p[1][1]) + (p[1][2] + p[1][3]);
  float u2 = (p[2][0] + p[2][1]) + (p[2][2] + p[2][3]);
  float u3 = (p[3][0] + p[3][1]) + (p[3][2] + p[3][3]);
  float rs = (u0 + u1) + (u2 + u3);
  rs += __shfl_xor(rs, 16);
  rs += __shfl_xor(rs, 32);
  l += rs;

  u32 wpk[4][2];
#pragma unroll
  for (int n = 0; n < 4; ++n) {
    wpk[n][0] = pkbf(p[n][0], p[n][1]);
    wpk[n][1] = pkbf(p[n][2], p[n][3]);
  }

  // redistribute P^T -> PV A-fragments (8 bpermutes; bijective instances)
  u32 rcv[2][2][2];
#pragma unroll
  for (int e = 0; e < 2; ++e) {
    const int src = fr + ((((fg & 1) << 1) | ((fg >> 1) ^ e)) << 4);
    const bool tsel = ((fg & 1) ^ e) != 0;
#pragma unroll
    for (int c = 0; c < 2; ++c)
#pragma unroll
      for (int hh = 0; hh < 2; ++hh) {
        u32 v = tsel ? wpk[(c << 1) | 1][hh] : wpk[(c << 1) | 0][hh];
        rcv[e][c][hh] = (u32)__shfl((int)v, src);
      }
  }
  const bool hi = (fg >> 1) != 0;
  u32x4 w0, w1;
#pragma unroll
  for (int a = 0; a < 2; ++a)
#pragma unroll
    for (int hh = 0; hh < 2; ++hh) {
      w0[2 * a + hh] = hi ? rcv[a ^ 1][0][hh] : rcv[a][0][hh];
      w1[2 * a + hh] = hi ? rcv[a ^ 1][1][hh] : rcv[a][1][hh];
    }
  pa[0] = __builtin_bit_cast(bf16x8, w0);
  pa[1] = __builtin_bit_cast(bf16x8, w1);
}

static __device__ __forceinline__ void write_out(
    __bf16* __restrict__ out, f32x4 (&o)[4], float l,
    int b, int hoff, int q0wt, int fg, int fr) {
  float linv = 1.f / l;
  float lo[4];
#pragma unroll
  for (int r = 0; r < 4; ++r)
    lo[r] = __shfl(linv, fg * 4 + r);
#pragma unroll
  for (int n = 0; n < 4; ++n)
#pragma unroll
    for (int r = 0; r < 4; ++r) {
      int t = q0wt + fg * 4 + r;
      out[((size_t)(b * 2048 + t)) * 1024 + hoff + n * 16 + fr] = (__bf16)(o[n][r] * lo[r]);
    }
}

// FA2-style causal flash attention with fused task pairs.
// Block = (bh, qb_long=31-i, qb_short=i): both q-tiles share (b,h), so staged
// K/V tiles and K/V fragment reads are shared; short task rides along for
// kt <= qb_short. Every block does ~33 tile-equivalents -> uniform makespan.
// Grid 512 x 256; dbuf gld16 staging with chunk-XOR swizzle (as R6).
// Q is pre-scaled by 0.125*log2(e) in GEMM1's epilogue.
__global__ __launch_bounds__(256, 2)
void attn_causal7(const __bf16* __restrict__ qk, const __bf16* __restrict__ vt,
                  __bf16* __restrict__ out) {
  constexpr float NEG = -1e30f;

  __shared__ __bf16 lK[2][4096];  // [buf][key(64) x dkchunk(8) x 8]
  __shared__ __bf16 lV[2][4096];  // [buf][dk(64) x keychunk(8) x 8]

  const int tid = threadIdx.x;
  const int lane = tid & 63, w = tid >> 6;
  const int fr = lane & 15, fg = lane >> 4;
  const int blk = blockIdx.x;
  const int rest = blk >> 3;
  const int bh = ((blk & 7) << 2) | (rest & 3);  // XCD-local bh group
  const int i = rest >> 2;                       // 0..15
  const int qb0 = 31 - i, qb1 = i;               // long, short tasks
  const int b = bh >> 4, h = bh & 15;
  const int q0w0 = (qb0 << 6) + (w << 4);
  const int q0w1 = (qb1 << 6) + (w << 4);
  const int hoff = h * 64;
  const size_t qkbase = (size_t)b * (2048 * 2048);
  const __bf16* kb = qk + qkbase + 1024 + hoff;                // K rows, stride 2048
  const __bf16* vtb = vt + (size_t)((b << 10) | hoff) * 2048;  // V^T rows, stride 2048

  bf16x8 qf0[2], qf1[2];
#pragma unroll
  for (int c = 0; c < 2; ++c) {
    qf0[c] = ld8(qk + qkbase + (size_t)(q0w0 + fr) * 2048 + hoff + c * 32 + fg * 8);
    qf1[c] = ld8(qk + qkbase + (size_t)(q0w1 + fr) * 2048 + hoff + c * 32 + fg * 8);
  }

  f32x4 o0[4] = {}, o1[4] = {};
  float m_0 = NEG, l_0 = 0.f, m_1 = NEG, l_1 = 0.f;

#define STAGE(bf, k0s)                                                        \
  do {                                                                        \
    _Pragma("unroll")                                                         \
    for (int jj = 0; jj < 2; ++jj) {                                          \
      const int q = (w << 1) | jj;                                            \
      const int v = (q << 6) | lane;                                          \
      const int row = v >> 3;                                                 \
      const int cc = (v & 7) ^ (row & 7);                                     \
      gld16(kb + (size_t)((k0s) + row) * 2048 + (cc << 3), &lK[bf][q << 9]);  \
      gld16(vtb + (size_t)row * 2048 + (k0s) + (cc << 3), &lV[bf][q << 9]);   \
    }                                                                         \
  } while (0)

  int buf = 0;
  STAGE(0, 0);
  __syncthreads();

  for (int kt = 0; kt <= qb0; ++kt) {
    const int k0 = kt << 6;
    if (kt < qb0) STAGE(buf ^ 1, k0 + 64);
    const bool act1 = (kt <= qb1);

    f32x4 s0[4] = {}, s1[4] = {};
#pragma unroll
    for (int c = 0; c < 2; ++c) {
      bf16x8 kfc[4];
#pragma unroll
      for (int n = 0; n < 4; ++n) {
        const int row = n * 16 + fr;
        const int sc = ((c << 2) | fg) ^ (row & 7);
        kfc[n] = ld8(&lK[buf][(row << 6) + (sc << 3)]);
      }
#pragma unroll
      for (int n = 0; n < 4; ++n)
        s0[n] = MFMA(kfc[n], qf0[c], s0[n]);
      if (act1) {
#pragma unroll
        for (int n = 0; n < 4; ++n)
          s1[n] = MFMA(kfc[n], qf1[c], s1[n]);
      }
    }

    bf16x8 pa0[2], pa1[2];
    softmax_step(s0, o0, m_0, l_0, pa0, kt == qb0, q0w0, k0, fg, fr);
    if (act1)
      softmax_step(s1, o1, m_1, l_1, pa1, kt == qb1, q0w1, k0, fg, fr);

#pragma unroll
    for (int c = 0; c < 2; ++c) {
      bf16x8 vfc[4];
#pragma unroll
      for (int n = 0; n < 4; ++n) {
        const int row = n * 16 + fr;
        const int sc = ((c << 2) | fg) ^ (row & 7);
        vfc[n] = ld8(&lV[buf][(row << 6) + (sc << 3)]);
      }
#pragma unroll
      for (int n = 0; n < 4; ++n)
        o0[n] = MFMA(pa0[c], vfc[n], o0[n]);
      if (act1) {
#pragma unroll
        for (int n = 0; n < 4; ++n)
          o1[n] = MFMA(pa1[c], vfc[n], o1[n]);
      }
    }

    __syncthreads();  // all waves done reading buf; vmcnt drained (next staged)
    buf ^= 1;
  }
#undef STAGE

  write_out(out, o0, l_0, b, hoff, q0w0, fg, fr);
  write_out(out, o1, l_1, b, hoff, q0w1, fg, fr);
}

extern "C" void kernel_launch(void* const* d_in, const int* in_sizes, int n_in,
                              void* d_out, int out_size, void* d_ws, size_t ws_size,
                              hipStream_t stream) {
  const float* x = (const float*)d_in[0];       // (2,2048,1024) fp32
  const float* w_qkv = (const float*)d_in[1];   // (3072,1024) fp32
  const float* w_o = (const float*)d_in[2];     // (1024,1024) fp32
  float* out = (float*)d_out;                   // (2,2048,1024) fp32

  const int M = 4096;  // B*T
  __bf16* qk = (__bf16*)d_ws;                                    // 4096 x 2048 bf16 (16MB)
  __bf16* vt = (__bf16*)((char*)d_ws + (size_t)M * 2048 * 2);    // 2048 x 2048 bf16 (8MB)
  __bf16* attn = (__bf16*)((char*)d_ws + (size_t)M * 3072 * 2);  // 4096 x 1024 bf16 (8MB)

  // bf16 copies of x and W_qkv live in d_out (dead before GEMM2 writes it)
  __bf16* xb = (__bf16*)d_out;
  __bf16* wqb = xb + 4194304;
  const int NX = 4194304;  // x elems

  cvt_f32_bf16<<<3584, 256, 0, stream>>>(x, xb, NX, w_qkv, wqb);

  // GEMM1: qkv = x @ W_qkv^T ; Q (pre-scaled), K -> qk, V -> vt transposed
  gemm3<128, true, true, false><<<(M / 128) * (3072 / 128), 256, 0, stream>>>(
      xb, (const void*)wqb, (void*)qk, vt, M, 3072, 1024);

  // causal attention (fused task pairs, uniform makespan)
  attn_causal7<<<512, 256, 0, stream>>>(qk, vt, attn);

  // GEMM2: out = attn @ W_o^T (BN=64 tiles: 512 blocks)
  gemm3<64, false, false, true><<<(M / 128) * (1024 / 64), 256, 0, stream>>>(
      attn, (const void*)w_o, (void*)out, nullptr, M, 1024, 1024);
}